// Round 19
// baseline (95.341 us; speedup 1.0000x reference)
//
#include <hip/hip_runtime.h>

#define SLOPE 0.1f
#define NEG_INF_F (-9000000000000000.0f)

typedef int            iv4    __attribute__((ext_vector_type(4)));
typedef float          fv4    __attribute__((ext_vector_type(4)));
typedef unsigned short u16;
typedef u16            u16v4  __attribute__((ext_vector_type(4)));
typedef __bf16         bf16x8 __attribute__((ext_vector_type(8)));

static __device__ __forceinline__ u16 f2bf(float x) {
    union { float f; unsigned u; } v; v.f = x;
    unsigned r = v.u + 0x7fffu + ((v.u >> 16) & 1u);   // round-nearest-even
    return (u16)(r >> 16);
}
static __device__ __forceinline__ float bf2f(u16 h) {
    union { unsigned u; float f; } q; q.u = ((unsigned)h) << 16; return q.f;
}

// LDS-only barrier: order LDS ops without draining outstanding global stores.
static __device__ __forceinline__ void lds_barrier() {
    asm volatile("s_waitcnt lgkmcnt(0)" ::: "memory");
    __builtin_amdgcn_s_barrier();
}

// Problem constants: S=8, N=2048, IN_F=256, OUT_F=64; rows = 16384.

// ---------------------------------------------------------------------------
// Kernel 0: transpose W_w [64][256] -> wT [256][64] (k-major).
// ---------------------------------------------------------------------------
__global__ void k_wt(const float* __restrict__ W, float* __restrict__ wT) {
    int idx = blockIdx.x * 256 + threadIdx.x;
    int k = idx >> 6, f = idx & 63;
    wT[idx] = W[f * 256 + k];
}

// ---------------------------------------------------------------------------
// Kernel A: h = inDoc @ W^T + b (f32) -- LDS-FREE, BARRIER-FREE.
// 512 blocks x 256 thr. Thread t: f-group fq=t&15 (f0..f0+3), rows rq*2..+1.
// w-frags read straight from wT (L1-hot, 16-lane coalesced + 4-way bcast);
// inDoc row float4s broadcast across the 16 fq lanes. Compiler pipelines
// the 6-load + 32-FMA body freely with no syncs.
// Outputs: hT bf16 [s][f][i], si/sj.
// ---------------------------------------------------------------------------
__global__ __launch_bounds__(256) void k_h(
    const float* __restrict__ inDoc, const float* __restrict__ wT,
    const float* __restrict__ Wb, const float* __restrict__ aw,
    u16* __restrict__ hT, float* __restrict__ si, float* __restrict__ sj)
{
    const int t  = threadIdx.x;
    const int R0 = blockIdx.x * 32;
    const int fq = t & 15, rq = t >> 4;
    const int f0 = fq << 2;

    const float* in0 = inDoc + (size_t)(R0 + rq * 2) * 256;
    const float* in1 = in0 + 256;

    float acc[2][4];
#pragma unroll
    for (int r = 0; r < 2; ++r)
#pragma unroll
        for (int c = 0; c < 4; ++c) acc[r][c] = 0.f;

#pragma unroll 2
    for (int k0 = 0; k0 < 256; k0 += 4) {
        fv4 w0 = *(const fv4*)(wT + (k0 + 0) * 64 + f0);
        fv4 w1 = *(const fv4*)(wT + (k0 + 1) * 64 + f0);
        fv4 w2 = *(const fv4*)(wT + (k0 + 2) * 64 + f0);
        fv4 w3 = *(const fv4*)(wT + (k0 + 3) * 64 + f0);
        fv4 a0 = *(const fv4*)(in0 + k0);
        fv4 a1 = *(const fv4*)(in1 + k0);
#pragma unroll
        for (int c = 0; c < 4; ++c) {
            acc[0][c] = fmaf(a0.x, w0[c], acc[0][c]);
            acc[0][c] = fmaf(a0.y, w1[c], acc[0][c]);
            acc[0][c] = fmaf(a0.z, w2[c], acc[0][c]);
            acc[0][c] = fmaf(a0.w, w3[c], acc[0][c]);
            acc[1][c] = fmaf(a1.x, w0[c], acc[1][c]);
            acc[1][c] = fmaf(a1.y, w1[c], acc[1][c]);
            acc[1][c] = fmaf(a1.z, w2[c], acc[1][c]);
            acc[1][c] = fmaf(a1.w, w3[c], acc[1][c]);
        }
    }

    float bw[4], a1v[4], a2v[4];
#pragma unroll
    for (int c = 0; c < 4; ++c) {
        bw[c]  = Wb[f0 + c];
        a1v[c] = aw[f0 + c];
        a2v[c] = aw[64 + f0 + c];
    }
    float sip[2], sjp[2];
#pragma unroll
    for (int r = 0; r < 2; ++r) {
#pragma unroll
        for (int c = 0; c < 4; ++c) acc[r][c] += bw[c];
        float x = 0.f, y = 0.f;
#pragma unroll
        for (int c = 0; c < 4; ++c) {
            x = fmaf(acc[r][c], a1v[c], x);
            y = fmaf(acc[r][c], a2v[c], y);
        }
        sip[r] = x; sjp[r] = y;
    }
    // reduce across the 16 fq lanes (xor 1,2,4,8 stays inside the group)
#pragma unroll
    for (int m = 1; m <= 8; m <<= 1) {
#pragma unroll
        for (int r = 0; r < 2; ++r) {
            sip[r] += __shfl_xor(sip[r], m, 64);
            sjp[r] += __shfl_xor(sjp[r], m, 64);
        }
    }
    const int rowbase = R0 + rq * 2;
    const int sR = rowbase >> 11;
    const int il = rowbase & 2047;
    u16* hTp = hT + (size_t)sR * 131072;   // [64][2048] per s
#pragma unroll
    for (int r = 0; r < 2; ++r)
#pragma unroll
        for (int c = 0; c < 4; ++c)
            hTp[(size_t)(f0 + c) * 2048 + il + r] = f2bf(acc[r][c]);
    if (fq == 0) {
#pragma unroll
        for (int r = 0; r < 2; ++r) {
            si[rowbase + r] = sip[r];
            sj[rowbase + r] = sjp[r];
        }
    }
}

// ---------------------------------------------------------------------------
// Kernel B: 1024 blocks x 512 threads (8 waves), 16 rows/block, (512,2).
// Phase 1 (all waves, 2 rows each): pipelined adj loads -> SKIP-MAX softmax
// (|score|<=~10 so exp is f32-safe; masked entries select 0 after exp;
// normalization identical mathematically) -> p bf16 into swizzled LDS ONLY.
// Phase 2 (wave-specialized): waves 0-3 full-K MFMA PV -> h_out; waves 4-7
// read p back, cvt bf16->f32, NT-store att as a dedicated pure-write burst.
// ---------------------------------------------------------------------------
__global__ __launch_bounds__(512, 2) void k_att(
    const int* __restrict__ adj, const u16* __restrict__ hT,
    const float* __restrict__ si, const float* __restrict__ sj,
    const float* __restrict__ ab_p,
    float* __restrict__ out_h, float* __restrict__ out_att)
{
    __shared__ __align__(16) u16 pB[16 * 2048];   // 64 KB bf16, XOR-swizzled
    const int t    = threadIdx.x;
    const int lane = t & 63, wv = t >> 6;         // wv 0..7
    const int i0   = blockIdx.x * 16;
    const int s    = i0 >> 11;
    const float ab = ab_p[0];
    const float* sjb = sj + (size_t)s * 2048;

    // sj hoist (32 floats/lane)
    fv4 sv[8];
#pragma unroll
    for (int c = 0; c < 8; ++c)
        sv[c] = *(const fv4*)(sjb + c * 256 + lane * 4);

    // ---- phase 1: 2 rows/wave, pipelined loads, LDS-only output ----
    const int r0  = wv * 2,      r1  = r0 + 1;
    const int fr0 = i0 + r0,     fr1 = i0 + r1;
    const float si0 = si[fr0] + ab;
    const float si1 = si[fr1] + ab;
    const int* a0 = adj + (size_t)fr0 * 2048;
    const int* a1 = adj + (size_t)fr1 * 2048;

    iv4 mA[8], mB[8];
#pragma unroll
    for (int c = 0; c < 8; ++c)
        mA[c] = __builtin_nontemporal_load((const iv4*)(a0 + c * 256 + lane * 4));
#pragma unroll
    for (int c = 0; c < 8; ++c)
        mB[c] = __builtin_nontemporal_load((const iv4*)(a1 + c * 256 + lane * 4));
    __builtin_amdgcn_sched_barrier(0);

#pragma unroll
    for (int rr = 0; rr < 2; ++rr) {
        const int r  = rr ? r1 : r0;
        const float sival = rr ? si1 : si0;
        iv4* mm = rr ? mB : mA;
        float v[32];
        float sum = 0.f;
        // one fused pass: mask -> lrelu -> exp -> select0 -> accumulate
#pragma unroll
        for (int c = 0; c < 8; ++c) {
            iv4 m = mm[c];
            float x, e;
            x = sival + sv[c].x; x = fmaxf(x, SLOPE * x); e = __expf(x);
            e = ((unsigned)(m.x + 1) <= 1u) ? 0.f : e; v[c*4+0] = e; sum += e;
            x = sival + sv[c].y; x = fmaxf(x, SLOPE * x); e = __expf(x);
            e = ((unsigned)(m.y + 1) <= 1u) ? 0.f : e; v[c*4+1] = e; sum += e;
            x = sival + sv[c].z; x = fmaxf(x, SLOPE * x); e = __expf(x);
            e = ((unsigned)(m.z + 1) <= 1u) ? 0.f : e; v[c*4+2] = e; sum += e;
            x = sival + sv[c].w; x = fmaxf(x, SLOPE * x); e = __expf(x);
            e = ((unsigned)(m.w + 1) <= 1u) ? 0.f : e; v[c*4+3] = e; sum += e;
        }
#pragma unroll
        for (int m2 = 1; m2 < 64; m2 <<= 1) sum += __shfl_xor(sum, m2, 64);
        const float inv = 1.0f / sum;

        const unsigned swz = (unsigned)(r & 7) << 4;
#pragma unroll
        for (int c = 0; c < 8; ++c) {
            const int j = c * 256 + lane * 4;
            u16v4 pk;
            pk.x = f2bf(v[c*4+0] * inv); pk.y = f2bf(v[c*4+1] * inv);
            pk.z = f2bf(v[c*4+2] * inv); pk.w = f2bf(v[c*4+3] * inv);
            unsigned byte = ((unsigned)(r * 4096 + j * 2)) ^ swz;
            *(u16v4*)((char*)pB + byte) = pk;
        }
    }
    lds_barrier();

    // ---- phase 2: wave-specialized ----
    if (wv < 4) {
        // MFMA PV, full K. Wave wv: f in [wv*16,+16), i in [i0,i0+16).
        const int m16   = lane & 15;
        const int klane = lane >> 4;
        const unsigned sw = (unsigned)(m16 & 7) << 4;
        const __bf16* hTs = (const __bf16*)hT + (size_t)s * 131072
                          + (size_t)(wv * 16 + m16) * 2048 + klane * 8;
        const unsigned bbase = (unsigned)(m16 * 4096 + klane * 16);
        fv4 acc = {0.f, 0.f, 0.f, 0.f};
#pragma unroll 4
        for (int k0 = 0; k0 < 2048; k0 += 32) {
            bf16x8 a = *(const bf16x8*)(hTs + k0);
            unsigned byte = (bbase + (unsigned)(k0 * 2)) ^ sw;
            bf16x8 b = *(const bf16x8*)((const char*)pB + byte);
            acc = __builtin_amdgcn_mfma_f32_16x16x32_bf16(a, b, acc, 0, 0, 0);
        }
        // C/D layout: col = lane&15 -> i, row = klane*4 + reg -> f
        const int orow = i0 + m16;
        float* op = out_h + (size_t)orow * 64 + wv * 16 + klane * 4;
        fv4 o;
        o.x = fmaxf(acc.x, SLOPE * acc.x);
        o.y = fmaxf(acc.y, SLOPE * acc.y);
        o.z = fmaxf(acc.z, SLOPE * acc.z);
        o.w = fmaxf(acc.w, SLOPE * acc.w);
        *(fv4*)op = o;
    } else {
        // Store waves: rows (wv-4)*4 .. +3 -> att (pure NT write burst).
        const int rw = (wv - 4) * 4;
#pragma unroll
        for (int rr = 0; rr < 4; ++rr) {
            const int r  = rw + rr;
            const int fr = i0 + r;
            float* attrow = out_att + (size_t)fr * 2048;
            const unsigned swz = (unsigned)(r & 7) << 4;
#pragma unroll
            for (int c = 0; c < 8; ++c) {
                const int j = c * 256 + lane * 4;
                unsigned byte = ((unsigned)(r * 4096 + j * 2)) ^ swz;
                u16v4 pk = *(const u16v4*)((const char*)pB + byte);
                fv4 pv;
                pv.x = bf2f(pk.x); pv.y = bf2f(pk.y);
                pv.z = bf2f(pk.z); pv.w = bf2f(pk.w);
                __builtin_nontemporal_store(pv, (fv4*)(attrow + j));
            }
        }
    }
}

// ---------------------------------------------------------------------------
extern "C" void kernel_launch(void* const* d_in, const int* in_sizes, int n_in,
                              void* d_out, int out_size, void* d_ws, size_t ws_size,
                              hipStream_t stream) {
    const float* inDoc = (const float*)d_in[0];   // [8][2048][256]
    const int*   adj   = (const int*)d_in[1];     // [8][2048][2048][1]
    const float* W_w   = (const float*)d_in[2];   // [64][256]
    const float* W_b   = (const float*)d_in[3];   // [64]
    const float* a_w   = (const float*)d_in[4];   // [1][128]
    const float* a_b   = (const float*)d_in[5];   // [1]

    float* out     = (float*)d_out;
    float* out_h   = out;                          // 16384*64
    float* out_att = out + (size_t)16384 * 64;     // 8*2048*2048

    float* ws = (float*)d_ws;
    float* wT = ws;                                // 256*64 f32
    u16*   hT = (u16*)(ws + 16384);                // 8*64*2048 bf16 = 2 MB
    float* si = (float*)(hT + (size_t)8 * 64 * 2048);
    float* sj = si + 16384;

    k_wt <<<64,   256, 0, stream>>>(W_w, wT);
    k_h  <<<512,  256, 0, stream>>>(inDoc, wT, W_b, a_w, hT, si, sj);
    k_att<<<1024, 512, 0, stream>>>(adj, hT, si, sj, a_b, out_h, out_att);
}

// Round 21
// 79.676 us; speedup vs baseline: 1.1966x; 1.1966x over previous
//
#include <hip/hip_runtime.h>

#define SLOPE 0.1f
#define NEG_INF_F (-9000000000000000.0f)

typedef int            iv4    __attribute__((ext_vector_type(4)));
typedef float          fv4    __attribute__((ext_vector_type(4)));
typedef unsigned short u16;
typedef u16            u16v4  __attribute__((ext_vector_type(4)));
typedef __bf16         bf16x8 __attribute__((ext_vector_type(8)));

static __device__ __forceinline__ u16 f2bf(float x) {
    union { float f; unsigned u; } v; v.f = x;
    unsigned r = v.u + 0x7fffu + ((v.u >> 16) & 1u);   // round-nearest-even
    return (u16)(r >> 16);
}
static __device__ __forceinline__ float bf2f(u16 h) {
    union { unsigned u; float f; } q; q.u = ((unsigned)h) << 16; return q.f;
}

// LDS-only barrier: order LDS ops without draining outstanding global stores.
static __device__ __forceinline__ void lds_barrier() {
    asm volatile("s_waitcnt lgkmcnt(0)" ::: "memory");
    __builtin_amdgcn_s_barrier();
}

// Problem constants: S=8, N=2048, IN_F=256, OUT_F=64; rows = 16384.

// ---------------------------------------------------------------------------
// Kernel A (round-18 version, measured best): h = inDoc @ W^T + b (f32),
// W transposed on the fly during LDS staging. Outputs: hT bf16 [s][f][i],
// si/sj. 32-row x 64-f tile per block (512 blocks = 2/CU).
// ---------------------------------------------------------------------------
__global__ __launch_bounds__(256) void k_h(
    const float* __restrict__ inDoc, const float* __restrict__ W,
    const float* __restrict__ Wb, const float* __restrict__ aw,
    u16* __restrict__ hT, float* __restrict__ si, float* __restrict__ sj)
{
    __shared__ float wTl[32 * 64];      // [k][f], 8 KB
    __shared__ float inl[32][36];       // [r][k], 4.6 KB
    const int t  = threadIdx.x;
    const int R0 = blockIdx.x * 32;
    const int fq = t & 15, rq = t >> 4;
    const int f0 = fq << 2;

    float acc[2][4];
#pragma unroll
    for (int r = 0; r < 2; ++r)
#pragma unroll
        for (int c = 0; c < 4; ++c) acc[r][c] = 0.f;

    for (int kc = 0; kc < 8; ++kc) {
        __syncthreads();
        {   // stage W chunk [64 f][32 k] -> wTl[k][f] (transpose in LDS)
            int f = t >> 2, q = t & 3;
            const float* src = W + f * 256 + kc * 32 + q * 8;
            float4 a = *(const float4*)src;
            float4 b = *(const float4*)(src + 4);
            wTl[(q*8+0)*64 + f] = a.x;  wTl[(q*8+1)*64 + f] = a.y;
            wTl[(q*8+2)*64 + f] = a.z;  wTl[(q*8+3)*64 + f] = a.w;
            wTl[(q*8+4)*64 + f] = b.x;  wTl[(q*8+5)*64 + f] = b.y;
            wTl[(q*8+6)*64 + f] = b.z;  wTl[(q*8+7)*64 + f] = b.w;
        }
        {   // stage inDoc chunk [32 rows][32 k]
            int r = t >> 3, q = t & 7;
            const float* src = inDoc + (size_t)(R0 + r) * 256 + kc * 32 + q * 4;
            *(float4*)&inl[r][q * 4] = *(const float4*)src;
        }
        __syncthreads();
#pragma unroll
        for (int k4 = 0; k4 < 8; ++k4) {
            const int k0 = k4 << 2;
            float w[4][4];
#pragma unroll
            for (int j = 0; j < 4; ++j) {
                float4 wv = *(const float4*)&wTl[(k0 + j) * 64 + f0];
                w[j][0] = wv.x; w[j][1] = wv.y; w[j][2] = wv.z; w[j][3] = wv.w;
            }
#pragma unroll
            for (int r = 0; r < 2; ++r) {
                float4 av = *(const float4*)&inl[rq * 2 + r][k0];
                float a[4] = {av.x, av.y, av.z, av.w};
#pragma unroll
                for (int j = 0; j < 4; ++j)
#pragma unroll
                    for (int c = 0; c < 4; ++c)
                        acc[r][c] = fmaf(a[j], w[j][c], acc[r][c]);
            }
        }
    }

    float bw[4], a1[4], a2[4];
#pragma unroll
    for (int c = 0; c < 4; ++c) {
        bw[c] = Wb[f0 + c];
        a1[c] = aw[f0 + c];
        a2[c] = aw[64 + f0 + c];
    }
    float sip[2], sjp[2];
#pragma unroll
    for (int r = 0; r < 2; ++r) {
#pragma unroll
        for (int c = 0; c < 4; ++c) acc[r][c] += bw[c];
        float x = 0.f, y = 0.f;
#pragma unroll
        for (int c = 0; c < 4; ++c) {
            x = fmaf(acc[r][c], a1[c], x);
            y = fmaf(acc[r][c], a2[c], y);
        }
        sip[r] = x; sjp[r] = y;
    }
#pragma unroll
    for (int m = 1; m <= 8; m <<= 1) {
#pragma unroll
        for (int r = 0; r < 2; ++r) {
            sip[r] += __shfl_xor(sip[r], m, 64);
            sjp[r] += __shfl_xor(sjp[r], m, 64);
        }
    }
    const int rowbase = R0 + rq * 2;
    const int sR = rowbase >> 11;
    const int il = rowbase & 2047;
    u16* hTp = hT + (size_t)sR * 131072;   // [64][2048] per s
#pragma unroll
    for (int r = 0; r < 2; ++r)
#pragma unroll
        for (int c = 0; c < 4; ++c)
            hTp[(size_t)(f0 + c) * 2048 + il + r] = f2bf(acc[r][c]);
    if (fq == 0) {
#pragma unroll
        for (int r = 0; r < 2; ++r) {
            si[rowbase + r] = sip[r];
            sj[rowbase + r] = sjp[r];
        }
    }
}

// ---------------------------------------------------------------------------
// Kernel B: 1024 blocks x 512 threads (8 waves), 16 rows/block, (512,2).
// Phase 1 (all waves, 2 rows each): pipelined adj loads -> SKIP-MAX softmax
// (|score|<=~10 so exp is f32-safe; masked entries select 0 after exp) ->
// p bf16 into swizzled LDS ONLY (no global stores).
// Phase 2 (wave-specialized): waves 0-3 full-K MFMA PV -> h_out; waves 4-7
// read p back, cvt bf16->f32, NT-store att as a dedicated pure-write burst.
// ---------------------------------------------------------------------------
__global__ __launch_bounds__(512, 2) void k_att(
    const int* __restrict__ adj, const u16* __restrict__ hT,
    const float* __restrict__ si, const float* __restrict__ sj,
    const float* __restrict__ ab_p,
    float* __restrict__ out_h, float* __restrict__ out_att)
{
    __shared__ __align__(16) u16 pB[16 * 2048];   // 64 KB bf16, XOR-swizzled
    const int t    = threadIdx.x;
    const int lane = t & 63, wv = t >> 6;         // wv 0..7
    const int i0   = blockIdx.x * 16;
    const int s    = i0 >> 11;
    const float ab = ab_p[0];
    const float* sjb = sj + (size_t)s * 2048;

    // sj hoist (32 floats/lane)
    fv4 sv[8];
#pragma unroll
    for (int c = 0; c < 8; ++c)
        sv[c] = *(const fv4*)(sjb + c * 256 + lane * 4);

    // ---- phase 1: 2 rows/wave, pipelined loads, LDS-only output ----
    const int r0  = wv * 2,      r1  = r0 + 1;
    const int fr0 = i0 + r0,     fr1 = i0 + r1;
    const float si0 = si[fr0] + ab;
    const float si1 = si[fr1] + ab;
    const int* a0 = adj + (size_t)fr0 * 2048;
    const int* a1 = adj + (size_t)fr1 * 2048;

    iv4 mA[8], mB[8];
#pragma unroll
    for (int c = 0; c < 8; ++c)
        mA[c] = __builtin_nontemporal_load((const iv4*)(a0 + c * 256 + lane * 4));
#pragma unroll
    for (int c = 0; c < 8; ++c)
        mB[c] = __builtin_nontemporal_load((const iv4*)(a1 + c * 256 + lane * 4));
    __builtin_amdgcn_sched_barrier(0);

#pragma unroll
    for (int rr = 0; rr < 2; ++rr) {
        const int r  = rr ? r1 : r0;
        const float sival = rr ? si1 : si0;
        iv4* mm = rr ? mB : mA;
        float v[32];
        float sum = 0.f;
        // one fused pass: mask -> lrelu -> exp -> select0 -> accumulate
#pragma unroll
        for (int c = 0; c < 8; ++c) {
            iv4 m = mm[c];
            float x, e;
            x = sival + sv[c].x; x = fmaxf(x, SLOPE * x); e = __expf(x);
            e = ((unsigned)(m.x + 1) <= 1u) ? 0.f : e; v[c*4+0] = e; sum += e;
            x = sival + sv[c].y; x = fmaxf(x, SLOPE * x); e = __expf(x);
            e = ((unsigned)(m.y + 1) <= 1u) ? 0.f : e; v[c*4+1] = e; sum += e;
            x = sival + sv[c].z; x = fmaxf(x, SLOPE * x); e = __expf(x);
            e = ((unsigned)(m.z + 1) <= 1u) ? 0.f : e; v[c*4+2] = e; sum += e;
            x = sival + sv[c].w; x = fmaxf(x, SLOPE * x); e = __expf(x);
            e = ((unsigned)(m.w + 1) <= 1u) ? 0.f : e; v[c*4+3] = e; sum += e;
        }
#pragma unroll
        for (int m2 = 1; m2 < 64; m2 <<= 1) sum += __shfl_xor(sum, m2, 64);
        const float inv = 1.0f / sum;

        const unsigned swz = (unsigned)(r & 7) << 4;
#pragma unroll
        for (int c = 0; c < 8; ++c) {
            const int j = c * 256 + lane * 4;
            u16v4 pk;
            pk.x = f2bf(v[c*4+0] * inv); pk.y = f2bf(v[c*4+1] * inv);
            pk.z = f2bf(v[c*4+2] * inv); pk.w = f2bf(v[c*4+3] * inv);
            unsigned byte = ((unsigned)(r * 4096 + j * 2)) ^ swz;
            *(u16v4*)((char*)pB + byte) = pk;
        }
    }
    lds_barrier();

    // ---- phase 2: wave-specialized ----
    if (wv < 4) {
        // MFMA PV, full K. Wave wv: f in [wv*16,+16), i in [i0,i0+16).
        const int m16   = lane & 15;
        const int klane = lane >> 4;
        const unsigned sw = (unsigned)(m16 & 7) << 4;
        const __bf16* hTs = (const __bf16*)hT + (size_t)s * 131072
                          + (size_t)(wv * 16 + m16) * 2048 + klane * 8;
        const unsigned bbase = (unsigned)(m16 * 4096 + klane * 16);
        fv4 acc = {0.f, 0.f, 0.f, 0.f};
#pragma unroll 4
        for (int k0 = 0; k0 < 2048; k0 += 32) {
            bf16x8 a = *(const bf16x8*)(hTs + k0);
            unsigned byte = (bbase + (unsigned)(k0 * 2)) ^ sw;
            bf16x8 b = *(const bf16x8*)((const char*)pB + byte);
            acc = __builtin_amdgcn_mfma_f32_16x16x32_bf16(a, b, acc, 0, 0, 0);
        }
        // C/D layout: col = lane&15 -> i, row = klane*4 + reg -> f
        const int orow = i0 + m16;
        float* op = out_h + (size_t)orow * 64 + wv * 16 + klane * 4;
        fv4 o;
        o.x = fmaxf(acc.x, SLOPE * acc.x);
        o.y = fmaxf(acc.y, SLOPE * acc.y);
        o.z = fmaxf(acc.z, SLOPE * acc.z);
        o.w = fmaxf(acc.w, SLOPE * acc.w);
        *(fv4*)op = o;
    } else {
        // Store waves: rows (wv-4)*4 .. +3 -> att (pure NT write burst).
        const int rw = (wv - 4) * 4;
#pragma unroll
        for (int rr = 0; rr < 4; ++rr) {
            const int r  = rw + rr;
            const int fr = i0 + r;
            float* attrow = out_att + (size_t)fr * 2048;
            const unsigned swz = (unsigned)(r & 7) << 4;
#pragma unroll
            for (int c = 0; c < 8; ++c) {
                const int j = c * 256 + lane * 4;
                unsigned byte = ((unsigned)(r * 4096 + j * 2)) ^ swz;
                u16v4 pk = *(const u16v4*)((const char*)pB + byte);
                fv4 pv;
                pv.x = bf2f(pk.x); pv.y = bf2f(pk.y);
                pv.z = bf2f(pk.z); pv.w = bf2f(pk.w);
                __builtin_nontemporal_store(pv, (fv4*)(attrow + j));
            }
        }
    }
}

// ---------------------------------------------------------------------------
extern "C" void kernel_launch(void* const* d_in, const int* in_sizes, int n_in,
                              void* d_out, int out_size, void* d_ws, size_t ws_size,
                              hipStream_t stream) {
    const float* inDoc = (const float*)d_in[0];   // [8][2048][256]
    const int*   adj   = (const int*)d_in[1];     // [8][2048][2048][1]
    const float* W_w   = (const float*)d_in[2];   // [64][256]
    const float* W_b   = (const float*)d_in[3];   // [64]
    const float* a_w   = (const float*)d_in[4];   // [1][128]
    const float* a_b   = (const float*)d_in[5];   // [1]

    float* out     = (float*)d_out;
    float* out_h   = out;                          // 16384*64
    float* out_att = out + (size_t)16384 * 64;     // 8*2048*2048

    float* ws = (float*)d_ws;
    u16*   hT = (u16*)(ws + 16384);                // 8*64*2048 bf16 = 2 MB
    float* si = (float*)(hT + (size_t)8 * 64 * 2048);
    float* sj = si + 16384;

    k_h  <<<512,  256, 0, stream>>>(inDoc, W_w, W_b, a_w, hT, si, sj);
    k_att<<<1024, 512, 0, stream>>>(adj, hT, si, sj, a_b, out_h, out_att);
}

// Round 23
// 79.460 us; speedup vs baseline: 1.1999x; 1.0027x over previous
//
#include <hip/hip_runtime.h>

#define SLOPE 0.1f
#define NEG_INF_F (-9000000000000000.0f)

typedef int            iv4    __attribute__((ext_vector_type(4)));
typedef float          fv4    __attribute__((ext_vector_type(4)));
typedef unsigned short u16;
typedef u16            u16v4  __attribute__((ext_vector_type(4)));
typedef __bf16         bf16x8 __attribute__((ext_vector_type(8)));

static __device__ __forceinline__ u16 f2bf(float x) {
    union { float f; unsigned u; } v; v.f = x;
    unsigned r = v.u + 0x7fffu + ((v.u >> 16) & 1u);   // round-nearest-even
    return (u16)(r >> 16);
}
static __device__ __forceinline__ float bf2f(u16 h) {
    union { unsigned u; float f; } q; q.u = ((unsigned)h) << 16; return q.f;
}

// LDS-only barrier: order LDS ops without draining outstanding global stores.
static __device__ __forceinline__ void lds_barrier() {
    asm volatile("s_waitcnt lgkmcnt(0)" ::: "memory");
    __builtin_amdgcn_s_barrier();
}

// Problem constants: S=8, N=2048, IN_F=256, OUT_F=64; rows = 16384.

// ---------------------------------------------------------------------------
// Kernel A: h = inDoc @ W^T + b (f32). W staged ONCE into LDS (64 KB,
// transposed, 1 barrier); inDoc read directly from global as float4
// broadcasts (L1-hot). Inner loop: 4 LDS + 2 global reads per 4-k, no
// barriers, no inl staging -> LDS traffic cut ~33%, all 16 syncs gone.
// 32 rows x 64 f per block (512 blocks = 2/CU at 64 KB LDS).
// ---------------------------------------------------------------------------
__global__ __launch_bounds__(256) void k_h(
    const float* __restrict__ inDoc, const float* __restrict__ W,
    const float* __restrict__ Wb, const float* __restrict__ aw,
    u16* __restrict__ hT, float* __restrict__ si, float* __restrict__ sj)
{
    __shared__ float wTl[256 * 64];     // [k][f], 64 KB
    const int t  = threadIdx.x;
    const int R0 = blockIdx.x * 32;
    const int fq = t & 15, rq = t >> 4;
    const int f0 = fq << 2;

    // stage W transposed: thread t covers f = t>>2, k in [(t&3)*64, +64)
    {
        const int f = t >> 2, q = t & 3;
        const float* src = W + f * 256 + q * 64;
#pragma unroll
        for (int j = 0; j < 64; j += 4) {
            float4 a = *(const float4*)(src + j);
            wTl[(q*64 + j + 0) * 64 + f] = a.x;
            wTl[(q*64 + j + 1) * 64 + f] = a.y;
            wTl[(q*64 + j + 2) * 64 + f] = a.z;
            wTl[(q*64 + j + 3) * 64 + f] = a.w;
        }
    }
    __syncthreads();

    const float* in0 = inDoc + (size_t)(R0 + rq * 2) * 256;
    const float* in1 = in0 + 256;

    float acc[2][4];
#pragma unroll
    for (int r = 0; r < 2; ++r)
#pragma unroll
        for (int c = 0; c < 4; ++c) acc[r][c] = 0.f;

#pragma unroll 4
    for (int k0 = 0; k0 < 256; k0 += 4) {
        fv4 w0 = *(const fv4*)&wTl[(k0 + 0) * 64 + f0];
        fv4 w1 = *(const fv4*)&wTl[(k0 + 1) * 64 + f0];
        fv4 w2 = *(const fv4*)&wTl[(k0 + 2) * 64 + f0];
        fv4 w3 = *(const fv4*)&wTl[(k0 + 3) * 64 + f0];
        fv4 a0 = *(const fv4*)(in0 + k0);
        fv4 a1 = *(const fv4*)(in1 + k0);
#pragma unroll
        for (int c = 0; c < 4; ++c) {
            acc[0][c] = fmaf(a0.x, w0[c], acc[0][c]);
            acc[0][c] = fmaf(a0.y, w1[c], acc[0][c]);
            acc[0][c] = fmaf(a0.z, w2[c], acc[0][c]);
            acc[0][c] = fmaf(a0.w, w3[c], acc[0][c]);
            acc[1][c] = fmaf(a1.x, w0[c], acc[1][c]);
            acc[1][c] = fmaf(a1.y, w1[c], acc[1][c]);
            acc[1][c] = fmaf(a1.z, w2[c], acc[1][c]);
            acc[1][c] = fmaf(a1.w, w3[c], acc[1][c]);
        }
    }

    float bw[4], a1v[4], a2v[4];
#pragma unroll
    for (int c = 0; c < 4; ++c) {
        bw[c]  = Wb[f0 + c];
        a1v[c] = aw[f0 + c];
        a2v[c] = aw[64 + f0 + c];
    }
    float sip[2], sjp[2];
#pragma unroll
    for (int r = 0; r < 2; ++r) {
#pragma unroll
        for (int c = 0; c < 4; ++c) acc[r][c] += bw[c];
        float x = 0.f, y = 0.f;
#pragma unroll
        for (int c = 0; c < 4; ++c) {
            x = fmaf(acc[r][c], a1v[c], x);
            y = fmaf(acc[r][c], a2v[c], y);
        }
        sip[r] = x; sjp[r] = y;
    }
    // reduce across the 16 fq lanes (xor 1,2,4,8 stays inside the group)
#pragma unroll
    for (int m = 1; m <= 8; m <<= 1) {
#pragma unroll
        for (int r = 0; r < 2; ++r) {
            sip[r] += __shfl_xor(sip[r], m, 64);
            sjp[r] += __shfl_xor(sjp[r], m, 64);
        }
    }
    const int rowbase = R0 + rq * 2;
    const int sR = rowbase >> 11;
    const int il = rowbase & 2047;
    u16* hTp = hT + (size_t)sR * 131072;   // [64][2048] per s
#pragma unroll
    for (int r = 0; r < 2; ++r)
#pragma unroll
        for (int c = 0; c < 4; ++c)
            hTp[(size_t)(f0 + c) * 2048 + il + r] = f2bf(acc[r][c]);
    if (fq == 0) {
#pragma unroll
        for (int r = 0; r < 2; ++r) {
            si[rowbase + r] = sip[r];
            sj[rowbase + r] = sjp[r];
        }
    }
}

// ---------------------------------------------------------------------------
// Kernel B (round-21 version, measured best): 1024 blocks x 512 threads
// (8 waves), 16 rows/block, (512,2). Phase 1: pipelined adj loads ->
// SKIP-MAX softmax -> p bf16 into swizzled LDS only. Phase 2
// (wave-specialized): waves 0-3 full-K MFMA PV -> h_out; waves 4-7 read p
// back, cvt bf16->f32, NT-store att as a dedicated pure-write burst.
// ---------------------------------------------------------------------------
__global__ __launch_bounds__(512, 2) void k_att(
    const int* __restrict__ adj, const u16* __restrict__ hT,
    const float* __restrict__ si, const float* __restrict__ sj,
    const float* __restrict__ ab_p,
    float* __restrict__ out_h, float* __restrict__ out_att)
{
    __shared__ __align__(16) u16 pB[16 * 2048];   // 64 KB bf16, XOR-swizzled
    const int t    = threadIdx.x;
    const int lane = t & 63, wv = t >> 6;         // wv 0..7
    const int i0   = blockIdx.x * 16;
    const int s    = i0 >> 11;
    const float ab = ab_p[0];
    const float* sjb = sj + (size_t)s * 2048;

    // sj hoist (32 floats/lane)
    fv4 sv[8];
#pragma unroll
    for (int c = 0; c < 8; ++c)
        sv[c] = *(const fv4*)(sjb + c * 256 + lane * 4);

    // ---- phase 1: 2 rows/wave, pipelined loads, LDS-only output ----
    const int r0  = wv * 2,      r1  = r0 + 1;
    const int fr0 = i0 + r0,     fr1 = i0 + r1;
    const float si0 = si[fr0] + ab;
    const float si1 = si[fr1] + ab;
    const int* a0 = adj + (size_t)fr0 * 2048;
    const int* a1 = adj + (size_t)fr1 * 2048;

    iv4 mA[8], mB[8];
#pragma unroll
    for (int c = 0; c < 8; ++c)
        mA[c] = __builtin_nontemporal_load((const iv4*)(a0 + c * 256 + lane * 4));
#pragma unroll
    for (int c = 0; c < 8; ++c)
        mB[c] = __builtin_nontemporal_load((const iv4*)(a1 + c * 256 + lane * 4));
    __builtin_amdgcn_sched_barrier(0);

#pragma unroll
    for (int rr = 0; rr < 2; ++rr) {
        const int r  = rr ? r1 : r0;
        const float sival = rr ? si1 : si0;
        iv4* mm = rr ? mB : mA;
        float v[32];
        float sum = 0.f;
        // one fused pass: mask -> lrelu -> exp -> select0 -> accumulate
#pragma unroll
        for (int c = 0; c < 8; ++c) {
            iv4 m = mm[c];
            float x, e;
            x = sival + sv[c].x; x = fmaxf(x, SLOPE * x); e = __expf(x);
            e = ((unsigned)(m.x + 1) <= 1u) ? 0.f : e; v[c*4+0] = e; sum += e;
            x = sival + sv[c].y; x = fmaxf(x, SLOPE * x); e = __expf(x);
            e = ((unsigned)(m.y + 1) <= 1u) ? 0.f : e; v[c*4+1] = e; sum += e;
            x = sival + sv[c].z; x = fmaxf(x, SLOPE * x); e = __expf(x);
            e = ((unsigned)(m.z + 1) <= 1u) ? 0.f : e; v[c*4+2] = e; sum += e;
            x = sival + sv[c].w; x = fmaxf(x, SLOPE * x); e = __expf(x);
            e = ((unsigned)(m.w + 1) <= 1u) ? 0.f : e; v[c*4+3] = e; sum += e;
        }
#pragma unroll
        for (int m2 = 1; m2 < 64; m2 <<= 1) sum += __shfl_xor(sum, m2, 64);
        const float inv = 1.0f / sum;

        const unsigned swz = (unsigned)(r & 7) << 4;
#pragma unroll
        for (int c = 0; c < 8; ++c) {
            const int j = c * 256 + lane * 4;
            u16v4 pk;
            pk.x = f2bf(v[c*4+0] * inv); pk.y = f2bf(v[c*4+1] * inv);
            pk.z = f2bf(v[c*4+2] * inv); pk.w = f2bf(v[c*4+3] * inv);
            unsigned byte = ((unsigned)(r * 4096 + j * 2)) ^ swz;
            *(u16v4*)((char*)pB + byte) = pk;
        }
    }
    lds_barrier();

    // ---- phase 2: wave-specialized ----
    if (wv < 4) {
        // MFMA PV, full K. Wave wv: f in [wv*16,+16), i in [i0,i0+16).
        const int m16   = lane & 15;
        const int klane = lane >> 4;
        const unsigned sw = (unsigned)(m16 & 7) << 4;
        const __bf16* hTs = (const __bf16*)hT + (size_t)s * 131072
                          + (size_t)(wv * 16 + m16) * 2048 + klane * 8;
        const unsigned bbase = (unsigned)(m16 * 4096 + klane * 16);
        fv4 acc = {0.f, 0.f, 0.f, 0.f};
#pragma unroll 4
        for (int k0 = 0; k0 < 2048; k0 += 32) {
            bf16x8 a = *(const bf16x8*)(hTs + k0);
            unsigned byte = (bbase + (unsigned)(k0 * 2)) ^ sw;
            bf16x8 b = *(const bf16x8*)((const char*)pB + byte);
            acc = __builtin_amdgcn_mfma_f32_16x16x32_bf16(a, b, acc, 0, 0, 0);
        }
        // C/D layout: col = lane&15 -> i, row = klane*4 + reg -> f
        const int orow = i0 + m16;
        float* op = out_h + (size_t)orow * 64 + wv * 16 + klane * 4;
        fv4 o;
        o.x = fmaxf(acc.x, SLOPE * acc.x);
        o.y = fmaxf(acc.y, SLOPE * acc.y);
        o.z = fmaxf(acc.z, SLOPE * acc.z);
        o.w = fmaxf(acc.w, SLOPE * acc.w);
        *(fv4*)op = o;
    } else {
        // Store waves: rows (wv-4)*4 .. +3 -> att (pure NT write burst).
        const int rw = (wv - 4) * 4;
#pragma unroll
        for (int rr = 0; rr < 4; ++rr) {
            const int r  = rw + rr;
            const int fr = i0 + r;
            float* attrow = out_att + (size_t)fr * 2048;
            const unsigned swz = (unsigned)(r & 7) << 4;
#pragma unroll
            for (int c = 0; c < 8; ++c) {
                const int j = c * 256 + lane * 4;
                unsigned byte = ((unsigned)(r * 4096 + j * 2)) ^ swz;
                u16v4 pk = *(const u16v4*)((const char*)pB + byte);
                fv4 pv;
                pv.x = bf2f(pk.x); pv.y = bf2f(pk.y);
                pv.z = bf2f(pk.z); pv.w = bf2f(pk.w);
                __builtin_nontemporal_store(pv, (fv4*)(attrow + j));
            }
        }
    }
}

// ---------------------------------------------------------------------------
extern "C" void kernel_launch(void* const* d_in, const int* in_sizes, int n_in,
                              void* d_out, int out_size, void* d_ws, size_t ws_size,
                              hipStream_t stream) {
    const float* inDoc = (const float*)d_in[0];   // [8][2048][256]
    const int*   adj   = (const int*)d_in[1];     // [8][2048][2048][1]
    const float* W_w   = (const float*)d_in[2];   // [64][256]
    const float* W_b   = (const float*)d_in[3];   // [64]
    const float* a_w   = (const float*)d_in[4];   // [1][128]
    const float* a_b   = (const float*)d_in[5];   // [1]

    float* out     = (float*)d_out;
    float* out_h   = out;                          // 16384*64
    float* out_att = out + (size_t)16384 * 64;     // 8*2048*2048

    float* ws = (float*)d_ws;
    u16*   hT = (u16*)(ws + 16384);                // 8*64*2048 bf16 = 2 MB
    float* si = (float*)(hT + (size_t)8 * 64 * 2048);
    float* sj = si + 16384;

    k_h  <<<512,  256, 0, stream>>>(inDoc, W_w, W_b, a_w, hT, si, sj);
    k_att<<<1024, 512, 0, stream>>>(adj, hT, si, sj, a_b, out_h, out_att);
}